// Round 9
// baseline (741.198 us; speedup 1.0000x reference)
//
#include <hip/hip_runtime.h>
#include <hip/hip_bf16.h>

typedef __bf16 bf16;
typedef unsigned long long u64;
typedef __bf16 bf16x8 __attribute__((ext_vector_type(8)));
typedef __bf16 bf16x4 __attribute__((ext_vector_type(4)));
typedef float f32x4 __attribute__((ext_vector_type(4)));

#define NB 4
#define T 8192
#define C 128
#define NBLK 40
#define XS 136   // LDS row stride (bf16): 128 ch + 8 pad

#define MFMA(a, b, c) __builtin_amdgcn_mfma_f32_16x16x32_bf16(a, b, c, 0, 0, 0)

__device__ __forceinline__ float bf2f(bf16 x){ return (float)x; }
__device__ __forceinline__ bf16 f2bf(float x){ return (bf16)x; }

__device__ __forceinline__ float ld(const void* p, int i, int isbf){
    return isbf ? bf2f(((const bf16*)p)[i]) : ((const float*)p)[i];
}

// Coherent 8B load (relaxed agent atomic -> sc0/sc1; compiler-managed waitcnt).
__device__ __forceinline__ bf16x4 ld8(const bf16* p){
    u64 v = __hip_atomic_load((const u64*)p, __ATOMIC_RELAXED, __HIP_MEMORY_SCOPE_AGENT);
    return __builtin_bit_cast(bf16x4, v);
}
// Coherent 16B store via asm (inputs only -> safe), caller drains vmcnt.
__device__ __forceinline__ void st16c(bf16* p, f32x4 v){
    asm volatile("global_store_dwordx4 %0, %1, off sc0 sc1" :: "v"(p), "v"(v) : "memory");
}

__global__ __launch_bounds__(64) void k_detect(const unsigned short* __restrict__ u,
                                               int* __restrict__ flag){
    unsigned short v = u[threadIdx.x * 2];
    int e = (v >> 7) & 255;
    bool sane = (e >= 100 && e <= 140) || ((v & 0x7FFF) == 0);
    unsigned long long m = __ballot(sane);
    if (threadIdx.x == 0) *flag = (__popcll(m) >= 48) ? 1 : 0;
}

// Canonicalize inputs (8 elems/thread). weff [40][256][256]: [o][c]=cw[o][c][0] (t-d),
// [o][128+c]=cw[o][c][1] (t); conv_w elem idx = blk*65536 + o*256 + c*2 + k.
__global__ __launch_bounds__(256) void k_prep(
    const void* __restrict__ conv_w, const void* __restrict__ post_w,
    const void* __restrict__ lin1_w, const void* __restrict__ lin2_w,
    const void* __restrict__ x,      const void* __restrict__ conv_b,
    const void* __restrict__ post_b, const void* __restrict__ pre_w,
    const void* __restrict__ pre_b,  const void* __restrict__ lin1_b,
    const void* __restrict__ lin2_b,
    bf16* __restrict__ weff, bf16* __restrict__ pwc,
    bf16* __restrict__ w1c,  bf16* __restrict__ w2c,
    float* __restrict__ xc,  float* __restrict__ cbf,
    float* __restrict__ pbf, float* __restrict__ misc,
    const int* __restrict__ flag){
    int f = *flag;
    int g = blockIdx.x * 256 + threadIdx.x;
    if (g < 327680){
        int blk = g >> 13, r = g & 8191, o = r >> 5, j = r & 31;
        int k = (j >= 16) ? 1 : 0;
        int base = blk * 65536 + o * 256 + (j * 8 - k * 128) * 2 + k;
        bf16x8 v;
#pragma unroll
        for (int m = 0; m < 8; m++) v[m] = f2bf(ld(conv_w, base + m * 2, f));
        *(bf16x8*)(weff + (size_t)g * 8) = v;
    } else if (g < 409600){
        int e = (g - 327680) * 8;
        bf16x8 v;
#pragma unroll
        for (int m = 0; m < 8; m++) v[m] = f2bf(ld(post_w, e + m, f));
        *(bf16x8*)(pwc + e) = v;
    } else if (g < 411648){
        int e = (g - 409600) * 8;
        bf16x8 v;
#pragma unroll
        for (int m = 0; m < 8; m++) v[m] = f2bf(ld(lin1_w, e + m, f));
        *(bf16x8*)(w1c + e) = v;
    } else if (g < 413696){
        int e = (g - 411648) * 8;
        bf16x8 v;
#pragma unroll
        for (int m = 0; m < 8; m++) v[m] = f2bf(ld(lin2_w, e + m, f));
        *(bf16x8*)(w2c + e) = v;
    } else if (g < 417792){
        int e = (g - 413696) * 8;
#pragma unroll
        for (int m = 0; m < 8; m++) xc[e + m] = ld(x, e + m, f);
    } else if (g < 419072){
        int e = (g - 417792) * 8;
#pragma unroll
        for (int m = 0; m < 8; m++) cbf[e + m] = ld(conv_b, e + m, f);
    } else if (g < 419712){
        int e = (g - 419072) * 8;
#pragma unroll
        for (int m = 0; m < 8; m++) pbf[e + m] = ld(post_b, e + m, f);
    } else if (g < 419808){
        int e = (g - 419712) * 8;
#pragma unroll
        for (int m = 0; m < 8; m++){
            int idx = e + m;
            if      (idx < 384) misc[idx] = ld(pre_w,  idx,       f);
            else if (idx < 512) misc[idx] = ld(pre_b,  idx - 384, f);
            else if (idx < 640) misc[idx] = ld(lin1_b, idx - 512, f);
            else                misc[idx] = ld(lin2_b, idx - 640, f);
        }
    }
}

__device__ __forceinline__ void wait_ge(unsigned* p, unsigned v){
    int guard = 0;
    while (__hip_atomic_load(p, __ATOMIC_RELAXED, __HIP_MEMORY_SCOPE_AGENT) < v){
        __builtin_amdgcn_s_sleep(1);
        if (++guard > (1 << 22)) break;   // failsafe
    }
}

// Store tail rows [128-nrows, 128) of Xo -> dst (coherent), then drain.
__device__ __forceinline__ void tail_store(const bf16* Xo, bf16* dst, int nrows, int tid){
    int ngr = nrows * 16;
    for (int g = tid; g < ngr; g += 512){
        int rr = 128 - nrows + (g >> 4), co = (g & 15) * 8;
        f32x4 v = *(const f32x4*)(Xo + rr * XS + co);
        st16c(dst + (size_t)rr * C + co, v);
    }
    asm volatile("s_waitcnt vmcnt(0)" ::: "memory");
}

#define CONV_TAPS(C0, C1, TAPOFS, BROW) \
  _Pragma("unroll") for (int kk = 0; kk < 4; kk++){ \
    int ko = (TAPOFS) + kk*32 + quad*8; \
    bf16x8 a0 = *(const bf16x8*)(wb + (size_t)(wv*16+lo)*256 + ko); \
    bf16x8 a1 = *(const bf16x8*)(wb + (size_t)(128+wv*16+lo)*256 + ko); \
    _Pragma("unroll") for (int ct = 0; ct < 4; ct++){ \
      const bf16* brow_ = (BROW); \
      bf16x8 bf_ = *(const bf16x8*)(brow_ + kk*32 + quad*8); \
      (C0)[ct] = MFMA(a0, bf_, (C0)[ct]); \
      (C1)[ct] = MFMA(a1, bf_, (C1)[ct]); } }

#define GLU_HALF(C0, C1, HOFS, DOS) \
  _Pragma("unroll") for (int ct = 0; ct < 4; ct++){ \
    int col = ct*16 + lo; bf16x4 sv; \
    _Pragma("unroll") for (int r = 0; r < 4; r++){ \
      int j = wv*16 + quad*4 + r; \
      float a_ = (C0)[ct][r] + cb[j]; \
      float g_ = (C1)[ct][r] + cb[128 + j]; \
      float s_ = a_ * (1.f/(1.f + __expf(-g_))); \
      ssum[((HOFS)+ct)*4 + r] += s_; sv[r] = f2bf(s_); } \
    if (DOS) *(bf16x4*)(S + col*XS + wv*16 + quad*4) = sv; }

#define POST_HALF(HOFS) { \
  f32x4 pacc[4] = {}; \
  _Pragma("unroll") for (int kk = 0; kk < 4; kk++){ \
    bf16x8 pa = *(const bf16x8*)(pwb + (wv*16+lo)*128 + kk*32 + quad*8); \
    _Pragma("unroll") for (int ct = 0; ct < 4; ct++){ \
      bf16x8 pbv = *(const bf16x8*)(S + (ct*16+lo)*XS + kk*32 + quad*8); \
      pacc[ct] = MFMA(pa, pbv, pacc[ct]); } } \
  _Pragma("unroll") for (int ct = 0; ct < 4; ct++) \
    _Pragma("unroll") for (int r = 0; r < 4; r++) \
      hreg[((HOFS)+ct)*4 + r] += pacc[ct][r] + pb[wv*16 + quad*4 + r]; }

#define XO_WRITE(HOFS, ROW0) \
  _Pragma("unroll") for (int ct = 0; ct < 4; ct++){ \
    bf16x4 hv; \
    _Pragma("unroll") for (int r = 0; r < 4; r++) hv[r] = f2bf(hreg[((HOFS)+ct)*4 + r]); \
    *(bf16x4*)(Xo + ((ROW0) + ct*16 + lo)*XS + wv*16 + quad*4) = hv; }

#define PUB() do{ if (tid == 0) __hip_atomic_store(prog + wg, (unsigned)(i + 2), \
                        __ATOMIC_RELAXED, __HIP_MEMORY_SCOPE_AGENT); }while(0)
#define STORE_PUB(NR) do{ if (do_store){ __syncthreads(); \
      tail_store(Xo, hout + hb + (size_t)t0 * C, (NR), tid); __syncthreads(); } \
      PUB(); }while(0)

// Persistent kernel, 256 WGs x 512 threads, 1 WG/CU. H1-first + early publish:
// layers with d<=64 & d_next<=64 publish their tail before any neighbor wait.
// 4-buffer h rotation pushes the WAR (cons) wait 3 stages back (off-chain).
__global__ __launch_bounds__(512) void k_main(
    const float* __restrict__ xc,  const float* __restrict__ misc,
    const bf16* __restrict__ weff, const float* __restrict__ cbf,
    const bf16* __restrict__ pwc,  const float* __restrict__ pbf,
    const bf16* __restrict__ w1c,  const bf16* __restrict__ w2c,
    bf16* __restrict__ hbase,
    unsigned* __restrict__ prog, unsigned* __restrict__ cons,
    void* __restrict__ outv, const int* __restrict__ flag)
{
    __shared__ __align__(16) bf16 Xo[128 * XS];  // own stage tile   (34,816 B)
    __shared__ __align__(16) bf16 Xh[128 * XS];  // halo tiles       (34,816 B)
    __shared__ __align__(16) bf16 S [ 64 * XS];  // skip/Z/U         (17,408 B)

    const size_t HSZ = (size_t)NB * T * C;       // elements per h buffer
    int tid  = threadIdx.x;
    int wg   = blockIdx.x;
    int b    = wg >> 6;
    int slab = wg & 63;
    int t0   = slab * 128;
    int wv = tid >> 6, ln = tid & 63, lo = ln & 15, quad = ln >> 4;
    const size_t hb = (size_t)b * T * C;

    float hreg[32];
    float ssum[32];

    // ---- pre-net: stage 0 into Xo + tail row 127 -> buf0 ----
    {
        const float* xr = xc + b * T;
#pragma unroll
        for (int ct = 0; ct < 8; ct++){
            int t = t0 + ct * 16 + lo;
            float x0 = (t >= 2) ? xr[t - 2] : 0.f;
            float x1 = (t >= 1) ? xr[t - 1] : 0.f;
            float x2 = xr[t];
            bf16x4 hv;
#pragma unroll
            for (int r = 0; r < 4; r++){
                int c = wv * 16 + quad * 4 + r;
                float acc = misc[384 + c] + misc[c*3]*x0 + misc[c*3+1]*x1 + misc[c*3+2]*x2;
                hreg[ct * 4 + r] = acc;
                hv[r] = f2bf(acc);
            }
            *(bf16x4*)(Xo + (ct * 16 + lo) * XS + wv * 16 + quad * 4) = hv;
        }
    }
#pragma unroll
    for (int k = 0; k < 32; k++) ssum[k] = 0.f;
    __syncthreads();
    if (slab < 63) tail_store(Xo, hbase + hb + (size_t)t0 * C, 1, tid);
    __syncthreads();
    if (tid == 0)
        __hip_atomic_store(prog + wg, 1u, __ATOMIC_RELAXED, __HIP_MEMORY_SCOPE_AGENT);

    // ---- 40 residual blocks ----
    for (int i = 0; i < NBLK; i++){
        int im = i % 10;
        int d  = 1 << im;
        int D  = (d >= 128) ? (d >> 7) : 1;
        int dn = (i < NBLK - 1) ? (1 << ((i + 1) % 10)) : 0;
        int Dn = (dn >= 128) ? (dn >> 7) : 1;
        int nst = (dn < 128) ? dn : 128;
        bool last = (i == NBLK - 1);
        bool do_store = !last && (slab + Dn <= 63);
        const bf16* hin  = hbase + (size_t)(i & 3) * HSZ;
        bf16*       hout = hbase + (size_t)((i + 1) & 3) * HSZ;
        const bf16* wb   = weff + ((size_t)i << 16);
        const bf16* pwb  = pwc  + i * 16384;
        const float* cb  = cbf + i * 256;
        const float* pb  = pbf + i * 128;
        int war_ok = 0, war_wg = 0; unsigned war_v = 0;
        if (!last && i >= 3){
            int d3 = 1 << ((i - 3) % 10); int D3 = (d3 >= 128) ? (d3 >> 7) : 1;
            if (slab + D3 <= 63){ war_ok = 1; war_wg = wg + D3; war_v = (unsigned)(i - 2); }
        }

        if (d <= 64){
            // ===== H1: fully chain-free (taps within own tile) =====
            f32x4 c0[4] = {}, c1[4] = {};
            CONV_TAPS(c0, c1, 128, Xo + (64 + ct*16 + lo) * XS);
            CONV_TAPS(c0, c1, 0,   Xo + (64 - d + ct*16 + lo) * XS);
            GLU_HALF(c0, c1, 4, true);
            __syncthreads();                       // S ready; all taps done
            POST_HALF(4);
            if (tid == 0 && war_ok) wait_ge(cons + war_wg, war_v);
            __syncthreads();                       // post reads done; WAR cleared
            XO_WRITE(4, 64);
            if (nst <= 64) STORE_PUB(nst);         // early publish!
            // ===== H0 =====
            if (tid == 0 && slab >= 1) wait_ge(prog + wg - 1, (unsigned)(i + 1));
            __syncthreads();
            for (int g = tid; g < d * 32; g += 512){
                int row = g >> 5, c4 = (g & 31) << 2;
                int t = t0 - d + row;
                bf16x4 v = {};
                if (t >= 0) v = ld8(hin + hb + (size_t)t * C + c4);
                *(bf16x4*)(Xh + row * XS + c4) = v;
            }
            __syncthreads();
            if (tid == 0)
                __hip_atomic_store(cons + wg, (unsigned)(i + 1),
                                   __ATOMIC_RELAXED, __HIP_MEMORY_SCOPE_AGENT);
            f32x4 e0[4] = {}, e1[4] = {};
            CONV_TAPS(e0, e1, 128, Xo + (ct*16 + lo) * XS);
            CONV_TAPS(e0, e1, 0,
                ((ct*16 + lo) < d ? Xh + (ct*16 + lo) * XS
                                  : Xo + (ct*16 + lo - d) * XS));
            GLU_HALF(e0, e1, 0, true);
            __syncthreads();
            POST_HALF(0);
            XO_WRITE(0, 0);
            if (nst > 64) STORE_PUB(128);
        } else {
            // ===== d >= 128: halo is entirely remote =====
            if (tid == 0){
                if (slab >= D) wait_ge(prog + wg - D, (unsigned)(i + 1));
                if (war_ok)    wait_ge(cons + war_wg, war_v);
            }
            __syncthreads();
#pragma unroll
            for (int j = 0; j < 8; j++){
                int g = j * 512 + tid;
                int vr = g >> 5, c4 = (g & 31) << 2;
                int t = t0 - d + vr;
                bf16x4 v = {};
                if (t >= 0) v = ld8(hin + hb + (size_t)t * C + c4);
                *(bf16x4*)(Xh + vr * XS + c4) = v;
            }
            __syncthreads();
            if (tid == 0 && !last)
                __hip_atomic_store(cons + wg, (unsigned)(i + 1),
                                   __ATOMIC_RELAXED, __HIP_MEMORY_SCOPE_AGENT);
            // H1
            f32x4 c0[4] = {}, c1[4] = {};
            CONV_TAPS(c0, c1, 128, Xo + (64 + ct*16 + lo) * XS);
            CONV_TAPS(c0, c1, 0,   Xh + (64 + ct*16 + lo) * XS);
            GLU_HALF(c0, c1, 4, !last);
            if (!last){
                __syncthreads();
                POST_HALF(4);
                __syncthreads();
                XO_WRITE(4, 64);
                if (nst <= 64) STORE_PUB(nst);     // im==9: publish after H1
            }
            // H0
            f32x4 e0[4] = {}, e1[4] = {};
            CONV_TAPS(e0, e1, 128, Xo + (ct*16 + lo) * XS);
            CONV_TAPS(e0, e1, 0,   Xh + (ct*16 + lo) * XS);
            GLU_HALF(e0, e1, 0, !last);
            if (!last){
                __syncthreads();
                POST_HALF(0);
                XO_WRITE(0, 0);
                if (nst > 64) STORE_PUB(128);
            }
        }
        __syncthreads();   // layer end: Xo/Xh/S stable for next layer
    }

    // ---- final: relu(ssum) -> lin1 -> relu -> lin2 -> out [T][B][C] ----
    const float* b1 = misc + 512;
    const float* b2 = misc + 640;
    int isbf = *flag;
    for (int H = 0; H < 2; H++){
#pragma unroll
        for (int ct = 0; ct < 4; ct++){
            int col = ct * 16 + lo;
            bf16x4 zv;
#pragma unroll
            for (int r = 0; r < 4; r++){
                float z = ssum[(H * 4 + ct) * 4 + r];
                zv[r] = f2bf(z > 0.f ? z : 0.f);
            }
            *(bf16x4*)(S + col * XS + wv * 16 + quad * 4) = zv;
        }
        __syncthreads();
        f32x4 a1[4] = {};
#pragma unroll
        for (int kk = 0; kk < 4; kk++){
            bf16x8 pa = *(const bf16x8*)(w1c + (wv*16 + lo) * 128 + kk*32 + quad*8);
#pragma unroll
            for (int ct = 0; ct < 4; ct++){
                bf16x8 pbv = *(const bf16x8*)(S + (ct*16 + lo) * XS + kk*32 + quad*8);
                a1[ct] = MFMA(pa, pbv, a1[ct]);
            }
        }
        __syncthreads();
#pragma unroll
        for (int ct = 0; ct < 4; ct++){
            int col = ct * 16 + lo;
            bf16x4 uv;
#pragma unroll
            for (int r = 0; r < 4; r++){
                int row = wv * 16 + quad * 4 + r;
                float u = a1[ct][r] + b1[row];
                uv[r] = f2bf(u > 0.f ? u : 0.f);
            }
            *(bf16x4*)(S + col * XS + wv * 16 + quad * 4) = uv;
        }
        __syncthreads();
        f32x4 a2[4] = {};
#pragma unroll
        for (int kk = 0; kk < 4; kk++){
            bf16x8 pa = *(const bf16x8*)(w2c + (wv*16 + lo) * 128 + kk*32 + quad*8);
#pragma unroll
            for (int ct = 0; ct < 4; ct++){
                bf16x8 pbv = *(const bf16x8*)(S + (ct*16 + lo) * XS + kk*32 + quad*8);
                a2[ct] = MFMA(pa, pbv, a2[ct]);
            }
        }
#pragma unroll
        for (int ct = 0; ct < 4; ct++){
            int col = t0 + H * 64 + ct * 16 + lo;
#pragma unroll
            for (int r = 0; r < 4; r++){
                int row = wv * 16 + quad * 4 + r;
                float v = a2[ct][r] + b2[row];
                size_t oi = ((size_t)col * NB + b) * C + row;
                if (isbf) ((bf16*)outv)[oi] = f2bf(v);
                else      ((float*)outv)[oi] = v;
            }
        }
        __syncthreads();
    }
}

extern "C" void kernel_launch(void* const* d_in, const int* in_sizes, int n_in,
                              void* d_out, int out_size, void* d_ws, size_t ws_size,
                              hipStream_t stream){
    const void* x      = d_in[0];
    const void* pre_w  = d_in[1];
    const void* pre_b  = d_in[2];
    const void* conv_w = d_in[3];
    const void* conv_b = d_in[4];
    const void* post_w = d_in[5];
    const void* post_b = d_in[6];
    const void* lin1w  = d_in[7];
    const void* lin1b  = d_in[8];
    const void* lin2w  = d_in[9];
    const void* lin2b  = d_in[10];

    char* ws = (char*)d_ws;
    bf16*     hbase = (bf16*)   (ws);                   // 4 x 8,388,608 B
    bf16*     weff  = (bf16*)   (ws + 33554432);        //  5,242,880 B
    bf16*     pwc   = (bf16*)   (ws + 38797312);        //  1,310,720 B
    bf16*     w1c   = (bf16*)   (ws + 40108032);        //     32,768 B
    bf16*     w2c   = (bf16*)   (ws + 40140800);        //     32,768 B
    float*    xc    = (float*)  (ws + 40173568);        //    131,072 B
    float*    cbf   = (float*)  (ws + 40304640);        //     40,960 B
    float*    pbf   = (float*)  (ws + 40345600);        //     20,480 B
    float*    misc  = (float*)  (ws + 40366080);        //      3,072 B
    int*      flag  = (int*)    (ws + 40369152);        //          4 B
    unsigned* prog  = (unsigned*)(ws + 40370176);       //      1,024 B
    unsigned* cons  = (unsigned*)(ws + 40371200);       //      1,024 B  (~40.4 MiB total)

    hipMemsetAsync(prog, 0, 2048, stream);
    k_detect<<<1, 64, 0, stream>>>((const unsigned short*)x, flag);
    k_prep<<<1640, 256, 0, stream>>>(conv_w, post_w, lin1w, lin2w, x, conv_b,
                                     post_b, pre_w, pre_b, lin1b, lin2b,
                                     weff, pwc, w1c, w2c, xc, cbf, pbf, misc, flag);

    const float* xc_c   = xc;   const float* misc_c = misc;
    const bf16*  weff_c = weff; const float* cbf_c  = cbf;
    const bf16*  pwc_c  = pwc;  const float* pbf_c  = pbf;
    const bf16*  w1c_c  = w1c;  const bf16*  w2c_c  = w2c;
    void* out_v = d_out;        const int* flag_c = flag;
    void* ka[13] = { &xc_c, &misc_c, &weff_c, &cbf_c, &pwc_c, &pbf_c,
                     &w1c_c, &w2c_c, &hbase, &prog, &cons, &out_v, &flag_c };
    hipLaunchCooperativeKernel((void*)k_main, dim3(256), dim3(512), ka, 0, stream);
}